// Round 1
// baseline (322.932 us; speedup 1.0000x reference)
//
#include <hip/hip_runtime.h>
#include <math.h>

// Shapes fixed by the reference: B=16, C=64, N=8192, F=8, K=6.
#define BB 16
#define CC 64
#define NN 8192
#define FF 8
#define KK 6
#define TILE 1024
#define NT 256

// y[f,row,n] = go^2 + ge^2 with
//   go = sum_k xs[n+k-2]*tcos[f,k] + xc[n+k-2]*tsin[f,k]
//   ge = sum_k xs[n+k-2]*tsin[f,k] - xc[n+k-2]*tcos[f,k]
// (XLA conv_general_dilated = cross-correlation, pad (2,3))
__global__ __launch_bounds__(NT) void temporal_filter_kernel(
    const float* __restrict__ x_sin, const float* __restrict__ x_cos,
    const float* __restrict__ ft, const float* __restrict__ tao,
    float* __restrict__ out) {
  __shared__ __align__(16) float s_sin[TILE + 8];
  __shared__ __align__(16) float s_cos[TILE + 8];
  __shared__ float s_ts[FF * KK];
  __shared__ float s_tc[FF * KK];

  const int tid = threadIdx.x;
  const int n0 = blockIdx.x * TILE;
  const int row = blockIdx.y;  // row = b*C + c

  // In-block filter bank: 48 threads, one (f,k) each. Full-precision expf/sinf/cosf.
  if (tid < FF * KK) {
    const int f = tid / KK;
    const float k = (float)(tid % KK);
    const float fts = 0.25f / (1.0f + expf(-ft[f]));
    // -K/log(0.2) = 6/ln(5) = 3.7280096073576714
    const float taos = 3.72800961f / (1.0f + expf(-tao[f]));
    const float env = expf(-k / taos);
    const float ph = 6.2831853071795865f * fts * k;
    s_ts[tid] = env * sinf(ph);
    s_tc[tid] = env * cosf(ph);
  }

  // Stage x tile with halo. s[i] <-> x[n0 + i - 4]; main part 16B-aligned at s[4].
  const float* xs = x_sin + (size_t)row * NN + n0;
  const float* xc = x_cos + (size_t)row * NN + n0;
  *(float4*)&s_sin[4 + tid * 4] = *(const float4*)&xs[tid * 4];
  *(float4*)&s_cos[4 + tid * 4] = *(const float4*)&xc[tid * 4];
  if (tid < 2) {
    const bool ok = (n0 + tid - 2) >= 0;  // left zero-pad (2)
    s_sin[2 + tid] = ok ? xs[tid - 2] : 0.0f;
    s_cos[2 + tid] = ok ? xc[tid - 2] : 0.0f;
  } else if (tid < 5) {
    const int j = tid - 2;  // right zero-pad (3)
    const bool ok = (n0 + TILE + j) < NN;
    s_sin[TILE + 4 + j] = ok ? xs[TILE + j] : 0.0f;
    s_cos[TILE + 4 + j] = ok ? xc[TILE + j] : 0.0f;
  }
  __syncthreads();

  // Each thread: 4 consecutive n positions, all 8 filters.
  // Taps needed: s[p+2 .. p+10]; read 3 aligned float4 (ds_read_b128, conflict-free).
  float a[12], b[12];
  {
    const float4* s4 = (const float4*)s_sin;
    float4 v0 = s4[tid], v1 = s4[tid + 1], v2 = s4[tid + 2];
    a[0] = v0.x; a[1] = v0.y; a[2]  = v0.z; a[3]  = v0.w;
    a[4] = v1.x; a[5] = v1.y; a[6]  = v1.z; a[7]  = v1.w;
    a[8] = v2.x; a[9] = v2.y; a[10] = v2.z; a[11] = v2.w;
  }
  {
    const float4* s4 = (const float4*)s_cos;
    float4 v0 = s4[tid], v1 = s4[tid + 1], v2 = s4[tid + 2];
    b[0] = v0.x; b[1] = v0.y; b[2]  = v0.z; b[3]  = v0.w;
    b[4] = v1.x; b[5] = v1.y; b[6]  = v1.z; b[7]  = v1.w;
    b[8] = v2.x; b[9] = v2.y; b[10] = v2.z; b[11] = v2.w;
  }

  float* outp = out + (size_t)row * NN + n0 + tid * 4;
#pragma unroll
  for (int f = 0; f < FF; ++f) {
    float r[4];
#pragma unroll
    for (int j = 0; j < 4; ++j) {
      float go = 0.0f, ge = 0.0f;
#pragma unroll
      for (int k = 0; k < KK; ++k) {
        const float ws = s_ts[f * KK + k];  // LDS broadcast (same addr all lanes)
        const float wc = s_tc[f * KK + k];
        const float vs = a[j + k + 2];
        const float vc = b[j + k + 2];
        go = fmaf(vs, wc, go);
        go = fmaf(vc, ws, go);
        ge = fmaf(vs, ws, ge);
        ge = fmaf(-vc, wc, ge);
      }
      r[j] = go * go + ge * ge;
    }
    *(float4*)(outp + (size_t)f * ((size_t)BB * CC * NN)) =
        make_float4(r[0], r[1], r[2], r[3]);
  }
}

extern "C" void kernel_launch(void* const* d_in, const int* in_sizes, int n_in,
                              void* d_out, int out_size, void* d_ws, size_t ws_size,
                              hipStream_t stream) {
  const float* x_sin = (const float*)d_in[0];
  const float* x_cos = (const float*)d_in[1];
  const float* ft    = (const float*)d_in[2];
  const float* tao   = (const float*)d_in[3];
  float* out = (float*)d_out;

  dim3 grid(NN / TILE, BB * CC);
  temporal_filter_kernel<<<grid, NT, 0, stream>>>(x_sin, x_cos, ft, tao, out);
}

// Round 2
// 321.182 us; speedup vs baseline: 1.0055x; 1.0055x over previous
//
#include <hip/hip_runtime.h>
#include <math.h>

// Shapes fixed by the reference: B=16, C=64, N=8192, F=8, K=6.
#define BB 16
#define CC 64
#define NN 8192
#define FF 8
#define KK 6
#define NT 256          // threads per block
#define PER_T 4         // n-positions per thread
#define NBLK_X (NN / (NT * PER_T))   // 8 blocks along n per row

typedef float float4v __attribute__((ext_vector_type(4)));

// --- Pre-kernel: compute the 8x6 sin/cos filter banks once into d_ws ---
// layout: ws[0..47] = env*sin(phase) [f*6+k], ws[48..95] = env*cos(phase)
__global__ void temporal_filter_weights(const float* __restrict__ ft,
                                        const float* __restrict__ tao,
                                        float* __restrict__ w) {
  const int tid = threadIdx.x;
  if (tid < FF * KK) {
    const int f = tid / KK;
    const float k = (float)(tid % KK);
    const float fts = 0.25f / (1.0f + expf(-ft[f]));
    // -K/log(0.2) = 6/ln(5)
    const float taos = 3.72800961f / (1.0f + expf(-tao[f]));
    const float env = expf(-k / taos);
    const float ph = 6.2831853071795865f * fts * k;
    w[tid] = env * sinf(ph);
    w[48 + tid] = env * cosf(ph);
  }
}

// --- Main kernel: no LDS, no barrier. 4 outputs/thread, all 8 filters. ---
// y[f,row,n] = go^2 + ge^2 with
//   go = sum_k xs[n+k-2]*tcos[f,k] + xc[n+k-2]*tsin[f,k]
//   ge = sum_k xs[n+k-2]*tsin[f,k] - xc[n+k-2]*tcos[f,k]
__global__ __launch_bounds__(NT) void temporal_filter_kernel(
    const float* __restrict__ x_sin, const float* __restrict__ x_cos,
    const float* __restrict__ wg, float* __restrict__ out) {
  const int tid = threadIdx.x;
  const int row = blockIdx.y;                 // b*C + c
  const int p = blockIdx.x * (NT * PER_T) + tid * PER_T;  // first n of this thread

  // Wave-uniform weight loads at literal offsets -> s_load into SGPRs.
  float wsin[FF * KK], wcos[FF * KK];
#pragma unroll
  for (int i = 0; i < FF * KK; ++i) {
    wsin[i] = wg[i];
    wcos[i] = wg[48 + i];
  }

  // Taps for outputs p..p+3 span x[p-2 .. p+6]: three aligned float4 at
  // p-4, p, p+4. Row-edge threads substitute zero-pad (predicate the load:
  // row 0 / last row would be OOB, other rows would read the wrong row).
  const float* xs = x_sin + (size_t)row * NN;
  const float* xc = x_cos + (size_t)row * NN;

  float a[12], b[12];
  float4v va0 = {0.f, 0.f, 0.f, 0.f}, vb0 = va0, va2 = va0, vb2 = va0;
  if (p != 0) {
    va0 = *(const float4v*)&xs[p - 4];
    vb0 = *(const float4v*)&xc[p - 4];
  }
  float4v va1 = *(const float4v*)&xs[p];
  float4v vb1 = *(const float4v*)&xc[p];
  if (p != NN - PER_T) {
    va2 = *(const float4v*)&xs[p + 4];
    vb2 = *(const float4v*)&xc[p + 4];
  }
#pragma unroll
  for (int j = 0; j < 4; ++j) {
    a[j] = va0[j]; a[4 + j] = va1[j]; a[8 + j] = va2[j];
    b[j] = vb0[j]; b[4 + j] = vb1[j]; b[8 + j] = vb2[j];
  }

  float* outp = out + (size_t)row * NN + p;
#pragma unroll
  for (int f = 0; f < FF; ++f) {
    float4v r;
#pragma unroll
    for (int j = 0; j < 4; ++j) {
      float go = 0.0f, ge = 0.0f;
#pragma unroll
      for (int k = 0; k < KK; ++k) {
        const float ws = wsin[f * KK + k];
        const float wc = wcos[f * KK + k];
        const float vs = a[j + k + 2];  // x[p+j+k-2]
        const float vc = b[j + k + 2];
        go = fmaf(vs, wc, go);
        go = fmaf(vc, ws, go);
        ge = fmaf(vs, ws, ge);
        ge = fmaf(-vc, wc, ge);
      }
      r[j] = go * go + ge * ge;
    }
    // Streaming store: output plane f, never re-read -> bypass L2 allocate.
    __builtin_nontemporal_store(
        r, (float4v*)(outp + (size_t)f * ((size_t)BB * CC * NN)));
  }
}

extern "C" void kernel_launch(void* const* d_in, const int* in_sizes, int n_in,
                              void* d_out, int out_size, void* d_ws, size_t ws_size,
                              hipStream_t stream) {
  const float* x_sin = (const float*)d_in[0];
  const float* x_cos = (const float*)d_in[1];
  const float* ft    = (const float*)d_in[2];
  const float* tao   = (const float*)d_in[3];
  float* out = (float*)d_out;
  float* wg  = (float*)d_ws;  // 96 floats of scratch

  temporal_filter_weights<<<dim3(1), 64, 0, stream>>>(ft, tao, wg);
  dim3 grid(NBLK_X, BB * CC);
  temporal_filter_kernel<<<grid, NT, 0, stream>>>(x_sin, x_cos, wg, out);
}